// Round 13
// baseline (162.834 us; speedup 1.0000x reference)
//
#include <hip/hip_runtime.h>

// Compact Bilinear Pooling reformulated as per-batch Gram GEMM + count-sketch
// scatter:  y_b[d] = sum_{i,j} w1[i] w2[j] (X_b X_b^T)[i,j] [(h1[i]+h2[j])%D==d]
// Round 13: r12 counters show the LDS pipe ~90% busy (7168 b128 reads + 4096
// adds + 19.6k conflict cyc per CU = the 91us). Reads scale with waves x tiles;
// halve them by 4 waves x 64 A-rows/wave (was 8 x 32): same 256-row block, same
// grid/NT, ds_read instrs 7168 -> 3584/CU. ~310 VGPR fits at 1 wave/SIMD (we
// are 1 block/CU by LDS anyway). ks-outer/set-inner keeps B in 8 VGPRs; wave
// DMAs 4 rows/tile -> in-loop vmcnt(8), same 6-buffer ring proof as r12.

#define D_PROJ 16384
#define C_CH   2048
#define HW_N   196
#define NKS    7                 // k-steps of 32 (K padded 196 -> 224)
#define KPAD   (NKS * 32)
#define B_N    16
#define THREADS 256              // 4 waves
#define SETS   4                 // 16-row i-sets per wave (64 rows/wave)
#define NT     64                // j-tiles per block (1024 cols / 16)
#define BUFS   6
#define ROWSH  448               // shorts per row (hi 224 | lo 224, swizzled)
#define TILE_SH (16 * ROWSH)
#define FPSCALE 65536.0f
#define INVSCALE (1.0f / 65536.0f)

typedef short  short8 __attribute__((ext_vector_type(8)));
typedef float  f32x4  __attribute__((ext_vector_type(4)));
typedef int    i32x4  __attribute__((ext_vector_type(4)));

static __device__ inline unsigned short f2bf(float f) {
    union { float f; unsigned u; } a; a.f = f;
    unsigned u = a.u;
    return (unsigned short)((u + 0x7FFFu + ((u >> 16) & 1u)) >> 16);  // RNE
}
static __device__ inline float bf2f(unsigned short h) {
    union { unsigned u; float f; } a; a.u = ((unsigned)h) << 16;
    return a.f;
}
static __device__ inline f32x4 mfma16(short8 a, short8 b, f32x4 c) {
    return __builtin_amdgcn_mfma_f32_16x16x32_bf16(a, b, c, 0, 0, 0);
}

// integer LDS atomic add (fire-and-forget; bank-parallel, unlike fp RMW)
static __device__ inline void lds_iadd(int* p, int v) {
    unsigned off = (unsigned)(uintptr_t)p;
    asm volatile("ds_add_u32 %0, %1" :: "v"(off), "v"(v) : "memory");
}
// fp32 LDS atomic add (fallback path only)
static __device__ inline void lds_fadd(float* p, float v) {
    unsigned off = (unsigned)(uintptr_t)p;
    asm volatile("ds_add_f32 %0, %1" :: "v"(off), "v"(v) : "memory");
}
// drain this wave's outstanding LDS ops (asm atomics invisible to compiler)
static __device__ inline void lds_drain() {
    asm volatile("s_waitcnt lgkmcnt(0)" ::: "memory");
    __builtin_amdgcn_sched_barrier(0);
}

// swizzled byte offset within a 896B row: block (ks,lo?,sub) XOR row-bits
static __device__ inline int swz_off(int ks, int lo64, int sub16, int row7) {
    return (((ks << 7) | lo64 | (sub16 << 4)) ^ (row7 << 4));
}

// ---- pre-convert: x (f32) -> split-bf16 hi/lo, swizzled rows of 896B ----
__global__ __launch_bounds__(256)
void cbp_convert(const float* __restrict__ x, unsigned short* __restrict__ ws) {
    const int id = blockIdx.x * 256 + threadIdx.x;
    const int total = B_N * C_CH * (KPAD / 8);
    if (id >= total) return;
    const int row = id / (KPAD / 8);
    const int sub = id - row * (KPAD / 8);   // 0..27
    const int k0  = sub * 8;
    const int ks  = k0 >> 5;
    const int s16 = (k0 >> 3) & 3;

    const float* xr = x + (size_t)row * HW_N;
    float v[8];
    if (k0 + 8 <= HW_N) {
        f32x4 p0 = *(const f32x4*)(xr + k0);
        f32x4 p1 = *(const f32x4*)(xr + k0 + 4);
#pragma unroll
        for (int e = 0; e < 4; ++e) { v[e] = p0[e]; v[4 + e] = p1[e]; }
    } else {
#pragma unroll
        for (int e = 0; e < 8; ++e) {
            const int k = k0 + e;
            v[e] = (k < HW_N) ? xr[k] : 0.0f;
        }
    }
    short8 hv, lv;
#pragma unroll
    for (int e = 0; e < 8; ++e) {
        unsigned short h = f2bf(v[e]);
        hv[e] = (short)h;
        lv[e] = (short)f2bf(v[e] - bf2f(h));
    }
    char* rowB = (char*)ws + (size_t)row * (ROWSH * 2);
    const int r7 = row & 7;
    *(short8*)(rowB + swz_off(ks, 0,  s16, r7)) = hv;
    *(short8*)(rowB + swz_off(ks, 64, s16, r7)) = lv;
}

// ---- stage one 16-row B tile into LDS via global_load_lds DMA ----
// 4 waves: wave w copies rows w, w+4, w+8, w+12; lanes 0..55 move 16B each.
// 4 vmcnt events per wave per tile.
static __device__ inline void stage_issue(const unsigned short* __restrict__ src0,
                                          unsigned short* dst0, int wave, int lane) {
    if (lane < 56) {
#pragma unroll
        for (int hlf = 0; hlf < 4; ++hlf) {
            const int row = wave + hlf * 4;
            const unsigned short* s = src0 + (size_t)row * ROWSH + (size_t)lane * 8;
            unsigned short* d = dst0 + (size_t)row * ROWSH;
            __builtin_amdgcn_global_load_lds(
                (const __attribute__((address_space(1))) void*)s,
                (__attribute__((address_space(3))) void*)d, 16, 0, 0);
        }
    }
}

// ---- main: Gram MFMA + int32 scatter; 4 waves x 64 A-rows ----
__global__ __launch_bounds__(THREADS, 1)
void cbp_gram13(const unsigned short* __restrict__ ws,
                const float* __restrict__ w1f,
                const float* __restrict__ w2f,
                const int*   __restrict__ h1,
                const int*   __restrict__ h2,
                int*         __restrict__ part) {
    __shared__ __align__(16) int hist[D_PROJ];                       // 64 KB
    __shared__ __align__(16) unsigned short stage[BUFS][TILE_SH];    // 84 KB
    __shared__ int pairsh[1024];                                     // 4 KB

    // XCD swizzle: id&7 -> XCD; batch b's 16 blocks share one XCD's L2
    const int id   = blockIdx.x;                 // 0..255
    const int b    = ((id & 7) << 1) | ((id >> 3) & 1);
    const int rest = id >> 4;                    // 0..15
    const int j0   = (rest & 1) * 1024;
    const int i0   = (rest >> 1) * 256;

    const int tid  = threadIdx.x;
    const int wave = tid >> 6;                   // 0..3
    const int lane = tid & 63;
    const int l15  = lane & 15;
    const int lgrp = lane >> 4;
    const int r7s  = (l15 & 7) << 4;             // read-side swizzle bits

    for (int t = tid; t < D_PROJ / 4; t += THREADS)
        ((i32x4*)hist)[t] = i32x4{0, 0, 0, 0};
    for (int t = tid; t < 1024; t += THREADS)    // pack h2 | sign(w2)<<31
        pairsh[t] = h2[j0 + t] | (w2f[j0 + t] < 0.f ? (int)0x80000000 : 0);

    // ---- A fragments: 4 sets of 16 rows per wave (64 i-rows), hi+lo ----
    short8 ah[SETS][NKS], al[SETS][NKS];
    int    binr[SETS][4];
    float  s1s[SETS][4];                         // w1 * 2^16 (exact +-65536)
#pragma unroll
    for (int s = 0; s < SETS; ++s) {
        const int irow = i0 + wave * 64 + s * 16 + l15;
        const char* rowA = (const char*)(ws + ((size_t)b * C_CH + irow) * ROWSH);
#pragma unroll
        for (int ks = 0; ks < NKS; ++ks) {
            ah[s][ks] = *(const short8*)(rowA + (((ks << 7) | (lgrp << 4)) ^ r7s));
            al[s][ks] = *(const short8*)(rowA + (((ks << 7) | 64 | (lgrp << 4)) ^ r7s));
        }
#pragma unroll
        for (int r = 0; r < 4; ++r) {
            const int ir = i0 + wave * 64 + s * 16 + lgrp * 4 + r;
            binr[s][r] = h1[ir];
            s1s[s][r]  = w1f[ir] * FPSCALE;
        }
    }

    // ---- prologue: stage tiles 0..3 (16 own DMAs); drain own LDS writes ----
    const unsigned short* jbase = ws + ((size_t)b * C_CH + j0) * ROWSH;
#pragma unroll
    for (int p = 0; p < 4; ++p)
        stage_issue(jbase + (size_t)p * TILE_SH, stage[p], wave, lane);
    asm volatile("s_waitcnt lgkmcnt(0)" ::: "memory");  // hist zero + pairsh stores

    // ---- interval loop: vmcnt(8); barrier; compute t,t+1; stage t+4,t+5 ----
    // FIFO at top: {t..t+3} = 16 DMAs; vmcnt(8) retires tiles t,t+1.
    for (int t = 0; t < NT; t += 2) {
        asm volatile("s_waitcnt vmcnt(8)" ::: "memory");
        __builtin_amdgcn_sched_barrier(0);
        asm volatile("s_barrier" ::: "memory");           // all waves' parts landed
        __builtin_amdgcn_sched_barrier(0);

        const int rb = t % BUFS;                          // 0,2,4 -> rb+1 no wrap
#pragma unroll
        for (int half = 0; half < 2; ++half) {
            const int tt  = t + half;
            const char* srow = (const char*)&stage[rb + half][(size_t)l15 * ROWSH];
            f32x4 acc0[SETS], acc1[SETS];
#pragma unroll
            for (int s = 0; s < SETS; ++s) {
                acc0[s] = f32x4{0.f, 0.f, 0.f, 0.f};
                acc1[s] = f32x4{0.f, 0.f, 0.f, 0.f};
            }
            // ks-outer, set-inner: B lives in 8 VGPRs, A stays resident
#pragma unroll
            for (int ks = 0; ks < NKS; ++ks) {
                const short8 bh = *(const short8*)(srow + (((ks << 7) | (lgrp << 4)) ^ r7s));
                const short8 bl = *(const short8*)(srow + (((ks << 7) | 64 | (lgrp << 4)) ^ r7s));
                // split-bf16: G = hi*hi + lo*hi + hi*lo (lo*lo ~2^-18, dropped)
                if (ks & 1) {
#pragma unroll
                    for (int s = 0; s < SETS; ++s) {
                        acc1[s] = mfma16(ah[s][ks], bh, acc1[s]);
                        acc1[s] = mfma16(al[s][ks], bh, acc1[s]);
                        acc1[s] = mfma16(ah[s][ks], bl, acc1[s]);
                    }
                } else {
#pragma unroll
                    for (int s = 0; s < SETS; ++s) {
                        acc0[s] = mfma16(ah[s][ks], bh, acc0[s]);
                        acc0[s] = mfma16(al[s][ks], bh, acc0[s]);
                        acc0[s] = mfma16(ah[s][ks], bl, acc0[s]);
                    }
                }
            }
            const unsigned pk  = (unsigned)pairsh[tt * 16 + l15];
            const int      h2v = (int)(pk & 0x3FFFu);
            const unsigned sg2 = pk & 0x80000000u;
            // C/D layout (HW-verified): col = lane&15 -> j, row = (lane>>4)*4+r -> i
#pragma unroll
            for (int s = 0; s < SETS; ++s) {
                const f32x4 g = acc0[s] + acc1[s];
#pragma unroll
                for (int r = 0; r < 4; ++r) {
                    int bin = binr[s][r] + h2v;
                    if (bin >= D_PROJ) bin -= D_PROJ;
                    const float fv = __uint_as_float(__float_as_uint(g[r] * s1s[s][r]) ^ sg2);
                    lds_iadd(&hist[bin], (int)rintf(fv));
                }
            }
        }

        // stage tiles t+4, t+5 (tail: dummy re-stage; bufs' last readers are
        // provably past the preceding barrier)
        int t4 = t + 4; if (t4 > NT - 1) t4 = NT - 1;
        int t5 = t + 5; if (t5 > NT - 1) t5 = NT - 1;
        const int sb = (t + 4) % BUFS;                    // 4,0,2 -> sb+1 no wrap
        stage_issue(jbase + (size_t)t4 * TILE_SH, stage[sb],     wave, lane);
        stage_issue(jbase + (size_t)t5 * TILE_SH, stage[sb + 1], wave, lane);
    }

    lds_drain();       // commit this wave's ds_adds (invisible to compiler)
    __syncthreads();   // all waves' adds visible
    // plain vectorized store of this block's partial histogram (no atomics)
    int* pslot = part + (size_t)(b * 16 + rest) * D_PROJ;
    for (int t = tid; t < D_PROJ / 4; t += THREADS)
        ((i32x4*)pslot)[t] = ((const i32x4*)hist)[t];
}

// ---- reduce 16 int partials per batch, rescale, signed-sqrt, L2 normalize ----
__global__ void cbp_finalize2(const int* __restrict__ part, float* __restrict__ y) {
    const int b   = blockIdx.x;
    const int tid = threadIdx.x;
    const int* pb = part + (size_t)b * 16 * D_PROJ;
    float* yb = y + (size_t)b * D_PROJ;
    __shared__ float partial[4];

    float ssum = 0.f;
    for (int t = tid; t < D_PROJ; t += 256) {
        int acc = 0;
#pragma unroll
        for (int s = 0; s < 16; ++s) acc += pb[(size_t)s * D_PROJ + t];
        float v = (float)acc * INVSCALE;
        float sg = copysignf(sqrtf(fabsf(v) + 1e-8f), v);
        yb[t] = sg;
        ssum += sg * sg;
    }
    const int lane = tid & 63, wv = tid >> 6;
#pragma unroll
    for (int off = 32; off > 0; off >>= 1) ssum += __shfl_down(ssum, off, 64);
    if (lane == 0) partial[wv] = ssum;
    __syncthreads();
    const float total = partial[0] + partial[1] + partial[2] + partial[3];
    const float inv = 1.0f / sqrtf(total + 1e-8f);
    for (int t = tid; t < D_PROJ; t += 256) yb[t] *= inv;
}

// ---------------- fallback (round-1 style, used if ws too small) --------------
static __device__ inline void cvt_split(const float (&v)[8], short8& hi, short8& lo) {
#pragma unroll
    for (int e = 0; e < 8; ++e) {
        unsigned short h = f2bf(v[e]);
        hi[e] = (short)h;
        lo[e] = (short)f2bf(v[e] - bf2f(h));
    }
}

__global__ __launch_bounds__(256, 2)
void cbp_gram_scatter(const float* __restrict__ x,
                      const float* __restrict__ w1f,
                      const float* __restrict__ w2f,
                      const int*   __restrict__ h1,
                      const int*   __restrict__ h2,
                      float*       __restrict__ y) {
    __shared__ float hist[D_PROJ];
    const int b    = blockIdx.y;
    const int i0   = blockIdx.x * 64;
    const int tid  = threadIdx.x;
    const int wave = tid >> 6;
    const int lane = tid & 63;
    const int l15  = lane & 15;
    const int lgrp = lane >> 4;

    for (int t = tid; t < D_PROJ; t += 256) hist[t] = 0.0f;
    const float* xb = x + (size_t)b * (C_CH * HW_N);

    const int    irow = i0 + wave * 16 + l15;
    const float* xa   = xb + (size_t)irow * HW_N;
    const float  w1s  = w1f[irow];
    short8 a_hi[NKS], a_lo[NKS];
#pragma unroll
    for (int ks = 0; ks < NKS; ++ks) {
        const int k0 = ks * 32 + lgrp * 8;
        float v[8];
#pragma unroll
        for (int e = 0; e < 8; ++e) {
            const int k = k0 + e;
            v[e] = (k < HW_N) ? xa[k] * w1s : 0.0f;
        }
        cvt_split(v, a_hi[ks], a_lo[ks]);
    }
    int bin1[4];
#pragma unroll
    for (int r = 0; r < 4; ++r) bin1[r] = h1[i0 + wave * 16 + lgrp * 4 + r];

    __syncthreads();

    for (int jt = 0; jt < C_CH / 16; ++jt) {
        const int    jrow = jt * 16 + l15;
        const float* xj   = xb + (size_t)jrow * HW_N;
        const float  w2s  = w2f[jrow];
        const int    h2j  = h2[jrow];
        f32x4 acc0 = {0.f, 0.f, 0.f, 0.f};
        f32x4 acc1 = {0.f, 0.f, 0.f, 0.f};
#pragma unroll
        for (int ks = 0; ks < NKS; ++ks) {
            const int k0 = ks * 32 + lgrp * 8;
            float v[8];
            if (ks < 6) {
                f32x4 p0 = *(const f32x4*)(xj + k0);
                f32x4 p1 = *(const f32x4*)(xj + k0 + 4);
#pragma unroll
                for (int e = 0; e < 4; ++e) { v[e] = p0[e]; v[4 + e] = p1[e]; }
            } else {
#pragma unroll
                for (int e = 0; e < 8; ++e) {
                    const int k = k0 + e;
                    v[e] = (k < HW_N) ? xj[k] : 0.0f;
                }
            }
#pragma unroll
            for (int e = 0; e < 8; ++e) v[e] *= w2s;
            short8 bhi, blo;
            cvt_split(v, bhi, blo);
            if (ks & 1) {
                acc1 = mfma16(a_hi[ks], bhi, acc1);
                acc1 = mfma16(a_hi[ks], blo, acc1);
                acc1 = mfma16(a_lo[ks], bhi, acc1);
            } else {
                acc0 = mfma16(a_hi[ks], bhi, acc0);
                acc0 = mfma16(a_hi[ks], blo, acc0);
                acc0 = mfma16(a_lo[ks], bhi, acc0);
            }
        }
        const f32x4 g = acc0 + acc1;
#pragma unroll
        for (int r = 0; r < 4; ++r) {
            int bin = bin1[r] + h2j;
            if (bin >= D_PROJ) bin -= D_PROJ;
            lds_fadd(&hist[bin], g[r]);
        }
    }

    lds_drain();
    __syncthreads();
    float* yb = y + (size_t)b * D_PROJ;
    for (int t = tid; t < D_PROJ; t += 256)
        atomicAdd(&yb[t], hist[t]);
}

__global__ void cbp_finalize(float* __restrict__ y) {
    const int b   = blockIdx.x;
    const int tid = threadIdx.x;
    float* yb = y + (size_t)b * D_PROJ;
    __shared__ float partial[4];

    float ssum = 0.f;
    for (int t = tid; t < D_PROJ; t += 256) {
        float v = yb[t];
        float s = copysignf(sqrtf(fabsf(v) + 1e-8f), v);
        yb[t] = s;
        ssum += s * s;
    }
    const int lane = tid & 63, wv = tid >> 6;
#pragma unroll
    for (int off = 32; off > 0; off >>= 1) ssum += __shfl_down(ssum, off, 64);
    if (lane == 0) partial[wv] = ssum;
    __syncthreads();
    const float total = partial[0] + partial[1] + partial[2] + partial[3];
    const float inv = 1.0f / sqrtf(total + 1e-8f);
    for (int t = tid; t < D_PROJ; t += 256) yb[t] *= inv;
}

extern "C" void kernel_launch(void* const* d_in, const int* in_sizes, int n_in,
                              void* d_out, int out_size, void* d_ws, size_t ws_size,
                              hipStream_t stream) {
    const float* x  = (const float*)d_in[0];
    const float* w1 = (const float*)d_in[1];
    const float* w2 = (const float*)d_in[2];
    const int*   h1 = (const int*)d_in[3];
    const int*   h2 = (const int*)d_in[4];
    float* y = (float*)d_out;

    const size_t need = (size_t)B_N * C_CH * ROWSH * 2 * sizeof(unsigned short);  // 58.72 MB (known-pass gate)
    const size_t planeBytes = (size_t)B_N * C_CH * ROWSH * sizeof(unsigned short);// 29.36 MB

    if (ws_size >= need) {
        unsigned short* wsp = (unsigned short*)d_ws;
        int* part = (int*)((char*)d_ws + planeBytes);       // 256 slots, 16.78 MB
        const int total = B_N * C_CH * (KPAD / 8);
        cbp_convert<<<(total + 255) / 256, 256, 0, stream>>>(x, wsp);
        cbp_gram13<<<256, THREADS, 0, stream>>>(wsp, w1, w2, h1, h2, part);
        cbp_finalize2<<<B_N, 256, 0, stream>>>(part, y);
    } else {
        hipMemsetAsync(y, 0, (size_t)B_N * D_PROJ * sizeof(float), stream);
        dim3 grid(C_CH / 64, B_N);
        cbp_gram_scatter<<<grid, 256, 0, stream>>>(x, w1, w2, h1, h2, y);
        cbp_finalize<<<B_N, 256, 0, stream>>>(y);
    }
}

// Round 14
// 132.214 us; speedup vs baseline: 1.2316x; 1.2316x over previous
//
#include <hip/hip_runtime.h>

// Compact Bilinear Pooling reformulated as per-batch Gram GEMM + count-sketch
// scatter:  y_b[d] = sum_{i,j} w1[i] w2[j] (X_b X_b^T)[i,j] [(h1[i]+h2[j])%D==d]
// Round 14: REVERT to r12 (best verified: 91us main / 132.5 total). r13's
// 4-wave/64-row trade regressed (compiler refused the 310-VGPR budget ->
// rematerialized A loads in-loop at 1 wave/SIMD). Single micro kept: fold the
// per-tile w2 sign into the 8 per-row scales once per tile (bit-exact sign
// XOR) instead of 16 per-product XORs.

#define D_PROJ 16384
#define C_CH   2048
#define HW_N   196
#define NKS    7                 // k-steps of 32 (K padded 196 -> 224)
#define KPAD   (NKS * 32)
#define B_N    16
#define THREADS 512
#define NT     64                // j-tiles per block (1024 cols / 16)
#define BUFS   6
#define ROWSH  448               // shorts per row (hi 224 | lo 224, swizzled)
#define TILE_SH (16 * ROWSH)
#define FPSCALE 65536.0f
#define INVSCALE (1.0f / 65536.0f)

typedef short  short8 __attribute__((ext_vector_type(8)));
typedef float  f32x4  __attribute__((ext_vector_type(4)));
typedef int    i32x4  __attribute__((ext_vector_type(4)));

static __device__ inline unsigned short f2bf(float f) {
    union { float f; unsigned u; } a; a.f = f;
    unsigned u = a.u;
    return (unsigned short)((u + 0x7FFFu + ((u >> 16) & 1u)) >> 16);  // RNE
}
static __device__ inline float bf2f(unsigned short h) {
    union { unsigned u; float f; } a; a.u = ((unsigned)h) << 16;
    return a.f;
}
static __device__ inline f32x4 mfma16(short8 a, short8 b, f32x4 c) {
    return __builtin_amdgcn_mfma_f32_16x16x32_bf16(a, b, c, 0, 0, 0);
}

// integer LDS atomic add (fire-and-forget; bank-parallel, unlike fp RMW)
static __device__ inline void lds_iadd(int* p, int v) {
    unsigned off = (unsigned)(uintptr_t)p;
    asm volatile("ds_add_u32 %0, %1" :: "v"(off), "v"(v) : "memory");
}
// fp32 LDS atomic add (fallback path only)
static __device__ inline void lds_fadd(float* p, float v) {
    unsigned off = (unsigned)(uintptr_t)p;
    asm volatile("ds_add_f32 %0, %1" :: "v"(off), "v"(v) : "memory");
}
// drain this wave's outstanding LDS ops (asm atomics invisible to compiler)
static __device__ inline void lds_drain() {
    asm volatile("s_waitcnt lgkmcnt(0)" ::: "memory");
    __builtin_amdgcn_sched_barrier(0);
}

// swizzled byte offset within a 896B row: block (ks,lo?,sub) XOR row-bits
static __device__ inline int swz_off(int ks, int lo64, int sub16, int row7) {
    return (((ks << 7) | lo64 | (sub16 << 4)) ^ (row7 << 4));
}

// ---- pre-convert: x (f32) -> split-bf16 hi/lo, swizzled rows of 896B ----
__global__ __launch_bounds__(256)
void cbp_convert(const float* __restrict__ x, unsigned short* __restrict__ ws) {
    const int id = blockIdx.x * 256 + threadIdx.x;
    const int total = B_N * C_CH * (KPAD / 8);
    if (id >= total) return;
    const int row = id / (KPAD / 8);
    const int sub = id - row * (KPAD / 8);   // 0..27
    const int k0  = sub * 8;
    const int ks  = k0 >> 5;
    const int s16 = (k0 >> 3) & 3;

    const float* xr = x + (size_t)row * HW_N;
    float v[8];
    if (k0 + 8 <= HW_N) {
        f32x4 p0 = *(const f32x4*)(xr + k0);
        f32x4 p1 = *(const f32x4*)(xr + k0 + 4);
#pragma unroll
        for (int e = 0; e < 4; ++e) { v[e] = p0[e]; v[4 + e] = p1[e]; }
    } else {
#pragma unroll
        for (int e = 0; e < 8; ++e) {
            const int k = k0 + e;
            v[e] = (k < HW_N) ? xr[k] : 0.0f;
        }
    }
    short8 hv, lv;
#pragma unroll
    for (int e = 0; e < 8; ++e) {
        unsigned short h = f2bf(v[e]);
        hv[e] = (short)h;
        lv[e] = (short)f2bf(v[e] - bf2f(h));
    }
    char* rowB = (char*)ws + (size_t)row * (ROWSH * 2);
    const int r7 = row & 7;
    *(short8*)(rowB + swz_off(ks, 0,  s16, r7)) = hv;
    *(short8*)(rowB + swz_off(ks, 64, s16, r7)) = lv;
}

// ---- stage one 16-row B tile into LDS via global_load_lds DMA ----
// wave w copies rows w and w+8; lanes 0..55 each move 16B; 2 vmcnt events/wave.
static __device__ inline void stage_issue(const unsigned short* __restrict__ src0,
                                          unsigned short* dst0, int wave, int lane) {
    if (lane < 56) {
#pragma unroll
        for (int hlf = 0; hlf < 2; ++hlf) {
            const int row = wave + hlf * 8;
            const unsigned short* s = src0 + (size_t)row * ROWSH + (size_t)lane * 8;
            unsigned short* d = dst0 + (size_t)row * ROWSH;
            __builtin_amdgcn_global_load_lds(
                (const __attribute__((address_space(1))) void*)s,
                (__attribute__((address_space(3))) void*)d, 16, 0, 0);
        }
    }
}

// ---- main: Gram MFMA + int32 scatter; 2-tile intervals, 4-tile lookahead ----
__global__ __launch_bounds__(THREADS, 2)
void cbp_gram14(const unsigned short* __restrict__ ws,
                const float* __restrict__ w1f,
                const float* __restrict__ w2f,
                const int*   __restrict__ h1,
                const int*   __restrict__ h2,
                int*         __restrict__ part) {
    __shared__ __align__(16) int hist[D_PROJ];                       // 64 KB
    __shared__ __align__(16) unsigned short stage[BUFS][TILE_SH];    // 84 KB
    __shared__ int pairsh[1024];                                     // 4 KB

    // XCD swizzle: id&7 -> XCD; batch b's 16 blocks share one XCD's L2
    const int id   = blockIdx.x;                 // 0..255
    const int b    = ((id & 7) << 1) | ((id >> 3) & 1);
    const int rest = id >> 4;                    // 0..15
    const int j0   = (rest & 1) * 1024;
    const int i0   = (rest >> 1) * 256;

    const int tid  = threadIdx.x;
    const int wave = tid >> 6;
    const int lane = tid & 63;
    const int l15  = lane & 15;
    const int lgrp = lane >> 4;
    const int r7s  = (l15 & 7) << 4;             // read-side swizzle bits

    for (int t = tid; t < D_PROJ / 4; t += THREADS)
        ((i32x4*)hist)[t] = i32x4{0, 0, 0, 0};
    for (int t = tid; t < 1024; t += THREADS)    // pack h2 | sign(w2)<<31
        pairsh[t] = h2[j0 + t] | (w2f[j0 + t] < 0.f ? (int)0x80000000 : 0);

    // ---- A fragments: 2 sets of 16 rows per wave (32 i-rows), hi+lo ----
    short8 ah[2][NKS], al[2][NKS];
    int    binr[2][4];
    float  s1s[2][4];                            // w1 * 2^16 (exact +-65536)
#pragma unroll
    for (int s = 0; s < 2; ++s) {
        const int irow = i0 + wave * 32 + s * 16 + l15;
        const char* rowA = (const char*)(ws + ((size_t)b * C_CH + irow) * ROWSH);
#pragma unroll
        for (int ks = 0; ks < NKS; ++ks) {
            ah[s][ks] = *(const short8*)(rowA + (((ks << 7) | (lgrp << 4)) ^ r7s));
            al[s][ks] = *(const short8*)(rowA + (((ks << 7) | 64 | (lgrp << 4)) ^ r7s));
        }
#pragma unroll
        for (int r = 0; r < 4; ++r) {
            const int ir = i0 + wave * 32 + s * 16 + lgrp * 4 + r;
            binr[s][r] = h1[ir];
            s1s[s][r]  = w1f[ir] * FPSCALE;
        }
    }

    // ---- prologue: stage tiles 0..3 (8 own DMAs); drain own LDS writes ----
    const unsigned short* jbase = ws + ((size_t)b * C_CH + j0) * ROWSH;
#pragma unroll
    for (int p = 0; p < 4; ++p)
        stage_issue(jbase + (size_t)p * TILE_SH, stage[p], wave, lane);
    asm volatile("s_waitcnt lgkmcnt(0)" ::: "memory");  // hist zero + pairsh stores

    // ---- interval loop: vmcnt(4); barrier; compute t,t+1; stage t+4,t+5 ----
    // FIFO at interval top: {t,t+1,t+2,t+3} = 8 DMAs; vmcnt(4) retires t,t+1.
    for (int t = 0; t < NT; t += 2) {
        asm volatile("s_waitcnt vmcnt(4)" ::: "memory");  // tiles t,t+1 DMA done
        __builtin_amdgcn_sched_barrier(0);
        asm volatile("s_barrier" ::: "memory");           // all waves' parts landed
        __builtin_amdgcn_sched_barrier(0);

        const int rb = t % BUFS;                          // 0,2,4 -> rb+1 no wrap
#pragma unroll
        for (int half = 0; half < 2; ++half) {
            const int tt  = t + half;
            const char* srow = (const char*)&stage[rb + half][(size_t)l15 * ROWSH];
            f32x4 a0 = {0.f,0.f,0.f,0.f}, a1 = {0.f,0.f,0.f,0.f};
            f32x4 b0 = {0.f,0.f,0.f,0.f}, b1 = {0.f,0.f,0.f,0.f};
#pragma unroll
            for (int ks = 0; ks < NKS; ++ks) {
                const short8 bh = *(const short8*)(srow + (((ks << 7) | (lgrp << 4)) ^ r7s));
                const short8 bl = *(const short8*)(srow + (((ks << 7) | 64 | (lgrp << 4)) ^ r7s));
                // split-bf16: G = hi*hi + lo*hi + hi*lo (lo*lo ~2^-18, dropped)
                if (ks & 1) {
                    a1 = mfma16(ah[0][ks], bh, a1);  b1 = mfma16(ah[1][ks], bh, b1);
                    a1 = mfma16(al[0][ks], bh, a1);  b1 = mfma16(al[1][ks], bh, b1);
                    a1 = mfma16(ah[0][ks], bl, a1);  b1 = mfma16(ah[1][ks], bl, b1);
                } else {
                    a0 = mfma16(ah[0][ks], bh, a0);  b0 = mfma16(ah[1][ks], bh, b0);
                    a0 = mfma16(al[0][ks], bh, a0);  b0 = mfma16(al[1][ks], bh, b0);
                    a0 = mfma16(ah[0][ks], bl, a0);  b0 = mfma16(ah[1][ks], bl, b0);
                }
            }
            const unsigned pk  = (unsigned)pairsh[tt * 16 + l15];
            const int      h2v = (int)(pk & 0x3FFFu);
            const unsigned sg2 = pk & 0x80000000u;
            // fold w2 sign into the 8 per-row scales ONCE per tile (bit-exact)
            float cs0[4], cs1[4];
#pragma unroll
            for (int r = 0; r < 4; ++r) {
                cs0[r] = __uint_as_float(__float_as_uint(s1s[0][r]) ^ sg2);
                cs1[r] = __uint_as_float(__float_as_uint(s1s[1][r]) ^ sg2);
            }
            // C/D layout (HW-verified): col = lane&15 -> j, row = (lane>>4)*4+r -> i
            const f32x4 g0 = a0 + a1;
            const f32x4 g1 = b0 + b1;
#pragma unroll
            for (int r = 0; r < 4; ++r) {
                int bin = binr[0][r] + h2v;
                if (bin >= D_PROJ) bin -= D_PROJ;
                lds_iadd(&hist[bin], (int)rintf(g0[r] * cs0[r]));
            }
#pragma unroll
            for (int r = 0; r < 4; ++r) {
                int bin = binr[1][r] + h2v;
                if (bin >= D_PROJ) bin -= D_PROJ;
                lds_iadd(&hist[bin], (int)rintf(g1[r] * cs1[r]));
            }
        }

        // stage tiles t+4, t+5 (tail: dummy re-stage of last tile; writes into
        // bufs whose last readers are provably past the preceding barrier)
        int t4 = t + 4; if (t4 > NT - 1) t4 = NT - 1;
        int t5 = t + 5; if (t5 > NT - 1) t5 = NT - 1;
        const int sb = (t + 4) % BUFS;                    // 4,0,2 -> sb+1 no wrap
        stage_issue(jbase + (size_t)t4 * TILE_SH, stage[sb],     wave, lane);
        stage_issue(jbase + (size_t)t5 * TILE_SH, stage[sb + 1], wave, lane);
    }

    lds_drain();       // commit this wave's ds_adds (invisible to compiler)
    __syncthreads();   // all waves' adds visible
    // plain vectorized store of this block's partial histogram (no atomics)
    int* pslot = part + (size_t)(b * 16 + rest) * D_PROJ;
    for (int t = tid; t < D_PROJ / 4; t += THREADS)
        ((i32x4*)pslot)[t] = ((const i32x4*)hist)[t];
}

// ---- reduce 16 int partials per batch, rescale, signed-sqrt, L2 normalize ----
__global__ void cbp_finalize2(const int* __restrict__ part, float* __restrict__ y) {
    const int b   = blockIdx.x;
    const int tid = threadIdx.x;
    const int* pb = part + (size_t)b * 16 * D_PROJ;
    float* yb = y + (size_t)b * D_PROJ;
    __shared__ float partial[4];

    float ssum = 0.f;
    for (int t = tid; t < D_PROJ; t += 256) {
        int acc = 0;
#pragma unroll
        for (int s = 0; s < 16; ++s) acc += pb[(size_t)s * D_PROJ + t];
        float v = (float)acc * INVSCALE;
        float sg = copysignf(sqrtf(fabsf(v) + 1e-8f), v);
        yb[t] = sg;
        ssum += sg * sg;
    }
    const int lane = tid & 63, wv = tid >> 6;
#pragma unroll
    for (int off = 32; off > 0; off >>= 1) ssum += __shfl_down(ssum, off, 64);
    if (lane == 0) partial[wv] = ssum;
    __syncthreads();
    const float total = partial[0] + partial[1] + partial[2] + partial[3];
    const float inv = 1.0f / sqrtf(total + 1e-8f);
    for (int t = tid; t < D_PROJ; t += 256) yb[t] *= inv;
}

// ---------------- fallback (round-1 style, used if ws too small) --------------
static __device__ inline void cvt_split(const float (&v)[8], short8& hi, short8& lo) {
#pragma unroll
    for (int e = 0; e < 8; ++e) {
        unsigned short h = f2bf(v[e]);
        hi[e] = (short)h;
        lo[e] = (short)f2bf(v[e] - bf2f(h));
    }
}

__global__ __launch_bounds__(256, 2)
void cbp_gram_scatter(const float* __restrict__ x,
                      const float* __restrict__ w1f,
                      const float* __restrict__ w2f,
                      const int*   __restrict__ h1,
                      const int*   __restrict__ h2,
                      float*       __restrict__ y) {
    __shared__ float hist[D_PROJ];
    const int b    = blockIdx.y;
    const int i0   = blockIdx.x * 64;
    const int tid  = threadIdx.x;
    const int wave = tid >> 6;
    const int lane = tid & 63;
    const int l15  = lane & 15;
    const int lgrp = lane >> 4;

    for (int t = tid; t < D_PROJ; t += 256) hist[t] = 0.0f;
    const float* xb = x + (size_t)b * (C_CH * HW_N);

    const int    irow = i0 + wave * 16 + l15;
    const float* xa   = xb + (size_t)irow * HW_N;
    const float  w1s  = w1f[irow];
    short8 a_hi[NKS], a_lo[NKS];
#pragma unroll
    for (int ks = 0; ks < NKS; ++ks) {
        const int k0 = ks * 32 + lgrp * 8;
        float v[8];
#pragma unroll
        for (int e = 0; e < 8; ++e) {
            const int k = k0 + e;
            v[e] = (k < HW_N) ? xa[k] * w1s : 0.0f;
        }
        cvt_split(v, a_hi[ks], a_lo[ks]);
    }
    int bin1[4];
#pragma unroll
    for (int r = 0; r < 4; ++r) bin1[r] = h1[i0 + wave * 16 + lgrp * 4 + r];

    __syncthreads();

    for (int jt = 0; jt < C_CH / 16; ++jt) {
        const int    jrow = jt * 16 + l15;
        const float* xj   = xb + (size_t)jrow * HW_N;
        const float  w2s  = w2f[jrow];
        const int    h2j  = h2[jrow];
        f32x4 acc0 = {0.f, 0.f, 0.f, 0.f};
        f32x4 acc1 = {0.f, 0.f, 0.f, 0.f};
#pragma unroll
        for (int ks = 0; ks < NKS; ++ks) {
            const int k0 = ks * 32 + lgrp * 8;
            float v[8];
            if (ks < 6) {
                f32x4 p0 = *(const f32x4*)(xj + k0);
                f32x4 p1 = *(const f32x4*)(xj + k0 + 4);
#pragma unroll
                for (int e = 0; e < 4; ++e) { v[e] = p0[e]; v[4 + e] = p1[e]; }
            } else {
#pragma unroll
                for (int e = 0; e < 8; ++e) {
                    const int k = k0 + e;
                    v[e] = (k < HW_N) ? xj[k] : 0.0f;
                }
            }
#pragma unroll
            for (int e = 0; e < 8; ++e) v[e] *= w2s;
            short8 bhi, blo;
            cvt_split(v, bhi, blo);
            if (ks & 1) {
                acc1 = mfma16(a_hi[ks], bhi, acc1);
                acc1 = mfma16(a_hi[ks], blo, acc1);
                acc1 = mfma16(a_lo[ks], bhi, acc1);
            } else {
                acc0 = mfma16(a_hi[ks], bhi, acc0);
                acc0 = mfma16(a_hi[ks], blo, acc0);
                acc0 = mfma16(a_lo[ks], bhi, acc0);
            }
        }
        const f32x4 g = acc0 + acc1;
#pragma unroll
        for (int r = 0; r < 4; ++r) {
            int bin = bin1[r] + h2j;
            if (bin >= D_PROJ) bin -= D_PROJ;
            lds_fadd(&hist[bin], g[r]);
        }
    }

    lds_drain();
    __syncthreads();
    float* yb = y + (size_t)b * D_PROJ;
    for (int t = tid; t < D_PROJ; t += 256)
        atomicAdd(&yb[t], hist[t]);
}

__global__ void cbp_finalize(float* __restrict__ y) {
    const int b   = blockIdx.x;
    const int tid = threadIdx.x;
    float* yb = y + (size_t)b * D_PROJ;
    __shared__ float partial[4];

    float ssum = 0.f;
    for (int t = tid; t < D_PROJ; t += 256) {
        float v = yb[t];
        float s = copysignf(sqrtf(fabsf(v) + 1e-8f), v);
        yb[t] = s;
        ssum += s * s;
    }
    const int lane = tid & 63, wv = tid >> 6;
#pragma unroll
    for (int off = 32; off > 0; off >>= 1) ssum += __shfl_down(ssum, off, 64);
    if (lane == 0) partial[wv] = ssum;
    __syncthreads();
    const float total = partial[0] + partial[1] + partial[2] + partial[3];
    const float inv = 1.0f / sqrtf(total + 1e-8f);
    for (int t = tid; t < D_PROJ; t += 256) yb[t] *= inv;
}

extern "C" void kernel_launch(void* const* d_in, const int* in_sizes, int n_in,
                              void* d_out, int out_size, void* d_ws, size_t ws_size,
                              hipStream_t stream) {
    const float* x  = (const float*)d_in[0];
    const float* w1 = (const float*)d_in[1];
    const float* w2 = (const float*)d_in[2];
    const int*   h1 = (const int*)d_in[3];
    const int*   h2 = (const int*)d_in[4];
    float* y = (float*)d_out;

    const size_t need = (size_t)B_N * C_CH * ROWSH * 2 * sizeof(unsigned short);  // 58.72 MB (known-pass gate)
    const size_t planeBytes = (size_t)B_N * C_CH * ROWSH * sizeof(unsigned short);// 29.36 MB

    if (ws_size >= need) {
        unsigned short* wsp = (unsigned short*)d_ws;
        int* part = (int*)((char*)d_ws + planeBytes);       // 256 slots, 16.78 MB
        const int total = B_N * C_CH * (KPAD / 8);
        cbp_convert<<<(total + 255) / 256, 256, 0, stream>>>(x, wsp);
        cbp_gram14<<<256, THREADS, 0, stream>>>(wsp, w1, w2, h1, h2, part);
        cbp_finalize2<<<B_N, 256, 0, stream>>>(part, y);
    } else {
        hipMemsetAsync(y, 0, (size_t)B_N * D_PROJ * sizeof(float), stream);
        dim3 grid(C_CH / 64, B_N);
        cbp_gram_scatter<<<grid, 256, 0, stream>>>(x, w1, w2, h1, h2, y);
        cbp_finalize<<<B_N, 256, 0, stream>>>(y);
    }
}